// Round 6
// baseline (154.652 us; speedup 1.0000x reference)
//
#include <hip/hip_runtime.h>

// Problem constants
#define DIM    1024
#define N_CLS  10
#define NB     16         // B tile width (classes padded with zero columns)
#define NROWS  16384
#define IMG    784
#define KSPLIT 8          // K-eighths; one wave each -> 8 waves/block
#define KW     128        // K per wave
#define CHUNKS 4          // KW / 32

typedef __attribute__((ext_vector_type(8))) short sh8;  // 8 bf16 (A/B frag)
typedef __attribute__((ext_vector_type(4))) float f4;   // 4 f32  (C/D frag)

// RNE pack of two fp32 into one dword of two bf16
__device__ __forceinline__ unsigned f2bf2(float lo, float hi) {
  unsigned a = __float_as_uint(lo);
  unsigned b = __float_as_uint(hi);
  a += 0x7FFFu + ((a >> 16) & 1u);
  b += 0x7FFFu + ((b >> 16) & 1u);
  return (a >> 16) | (b & 0xFFFF0000u);
}

__device__ __forceinline__ unsigned short f2bf(float x) {
  unsigned a = __float_as_uint(x);
  a += 0x7FFFu + ((a >> 16) & 1u);
  return (unsigned short)(a >> 16);
}

__device__ __forceinline__ sh8 pack8(f4 v0, f4 v1) {
  union {
    unsigned u[4];
    sh8 s;
  } r;
  r.u[0] = f2bf2(v0.x, v0.y);
  r.u[1] = f2bf2(v0.z, v0.w);
  r.u[2] = f2bf2(v1.x, v1.y);
  r.u[3] = f2bf2(v1.z, v1.w);
  return r.s;
}

// ---------------------------------------------------------------------------
// Kernel 1: refb[c][d] = bf16( canon[c][d] / ||canon[c]|| ), zero-padded to
// d<DIM, c<NB. Fully rewritten every launch (d_ws is re-poisoned).
// ---------------------------------------------------------------------------
__global__ void ref_prep_kernel(const float* __restrict__ canon,
                                unsigned short* __restrict__ refb) {
  __shared__ float red[256];
  const int c = blockIdx.x;
  const int t = threadIdx.x;

  float inv = 0.f;
  if (c < N_CLS) {
    const float* src = canon + c * IMG;
    float ss = 0.f;
    for (int d = t; d < IMG; d += 256) {
      float v = src[d];
      ss += v * v;
    }
    red[t] = ss;
    __syncthreads();
    for (int s = 128; s > 0; s >>= 1) {
      if (t < s) red[t] += red[t + s];
      __syncthreads();
    }
    inv = 1.0f / sqrtf(red[0]);
  }

  for (int d = t; d < DIM; d += 256) {
    float v = (c < N_CLS && d < IMG) ? canon[c * IMG + d] * inv : 0.f;
    refb[c * DIM + d] = f2bf(v);
  }
}

// ---------------------------------------------------------------------------
// Kernel 2: MFMA GEMM, fused re/im + |.|^2. 1024 blocks x 512 threads
// (8 waves). Block = one 16-row stripe; wave wv owns K-eighth [128wv,128wv+128).
// 8192 waves total = 32 waves/CU: R1-R5 all died because the allocator
// serializes in-flight loads (R5: VGPR_Count=32 -> ~1 outstanding load/wave,
// 4.7 B/cyc/CU). 32 independent latency chains/CU x >=1KB >= 19 B/cyc demand
// beats the 10 B/cyc HBM ceiling WITHOUT winning the pipelining fight.
// B operand in regs (16 VGPR/wave), K-loop = z loads + pack + 2 MFMA only.
// One padded-LDS combine (8 partials) per block, once.
// C/D map (R5-verified): col=lane&15, row=(lane>>4)*4+reg.
// ---------------------------------------------------------------------------
__global__ __launch_bounds__(512, 8) void swaptest_kernel(
    const float* __restrict__ zre, const float* __restrict__ zim,
    const unsigned short* __restrict__ refb, float* __restrict__ out) {
  __shared__ float part[KSPLIT][64][9];  // pad 8->9: conflict-free, 18 KB

  const int tid  = threadIdx.x;
  const int lane = tid & 63;
  const int wv   = tid >> 6;   // K-eighth 0..7
  const int mrow = lane & 15;  // A row within stripe == B class col
  const int kq   = lane >> 4;  // k-quad

  const int row   = blockIdx.x * 16 + mrow;
  const int kbase = wv * KW + kq * 8;

  // B fragments for this wave's K range: 4 chunks x 4 VGPRs
  sh8 bfrag[CHUNKS];
#pragma unroll
  for (int i = 0; i < CHUNKS; ++i)
    bfrag[i] = *(const sh8*)&refb[mrow * DIM + kbase + i * 32];

  const float* pre = zre + (size_t)row * DIM + kbase;
  const float* pim = zim + (size_t)row * DIM + kbase;

  f4 accre = {0.f, 0.f, 0.f, 0.f};
  f4 accim = {0.f, 0.f, 0.f, 0.f};

#pragma unroll
  for (int i = 0; i < CHUNKS; ++i) {
    const f4 cre0 = *(const f4*)(pre + i * 32);
    const f4 cre1 = *(const f4*)(pre + i * 32 + 4);
    const f4 cim0 = *(const f4*)(pim + i * 32);
    const f4 cim1 = *(const f4*)(pim + i * 32 + 4);
    accre = __builtin_amdgcn_mfma_f32_16x16x32_bf16(pack8(cre0, cre1),
                                                    bfrag[i], accre, 0, 0, 0);
    accim = __builtin_amdgcn_mfma_f32_16x16x32_bf16(pack8(cim0, cim1),
                                                    bfrag[i], accim, 0, 0, 0);
  }

  // ---- one-time K-split combine ----
#pragma unroll
  for (int r = 0; r < 4; ++r) {
    part[wv][lane][r]     = accre[r];
    part[wv][lane][4 + r] = accim[r];
  }
  __syncthreads();

  if (tid < 16 * N_CLS) {
    const int r = tid / N_CLS;        // output row within stripe
    const int c = tid - r * N_CLS;    // class
    const int pl = ((r >> 2) << 4) | c;  // lane holding (r,c): lane>>4=r>>2
    const int reg = r & 3;
    float are = 0.f, aim = 0.f;
#pragma unroll
    for (int w = 0; w < KSPLIT; ++w) {
      are += part[w][pl][reg];
      aim += part[w][pl][4 + reg];
    }
    out[(size_t)(blockIdx.x * 16 + r) * N_CLS + c] = are * are + aim * aim;
  }
}

// ---------------------------------------------------------------------------
extern "C" void kernel_launch(void* const* d_in, const int* in_sizes, int n_in,
                              void* d_out, int out_size, void* d_ws,
                              size_t ws_size, hipStream_t stream) {
  const float* z_re = (const float*)d_in[0];
  const float* z_im = (const float*)d_in[1];
  const float* canon = (const float*)d_in[2];
  float* out = (float*)d_out;
  unsigned short* refb = (unsigned short*)d_ws;  // 16 * 1024 * 2 B = 32 KiB

  ref_prep_kernel<<<NB, 256, 0, stream>>>(canon, refb);

  const int nblk = NROWS / 16;  // 1024 blocks x 512 threads
  swaptest_kernel<<<nblk, 512, 0, stream>>>(z_re, z_im, refb, out);
}